// Round 7
// baseline (272.244 us; speedup 1.0000x reference)
//
#include <hip/hip_runtime.h>

#define NN 50000
#define NE 800000
#define D  64
#define NB 782        // buckets of 64 nodes: ceil(50000/64)
#define NBLK 256      // p12 blocks
#define CHUNK 3125    // NBLK * CHUNK == NE exactly
#define CAP 1536      // per-bucket slot cap (mean 1024, +6 sigma ~ 1216)
#define CAPTOT (NB * CAP)

// bf16 helpers (raw ushort storage, fp32 math)
__device__ __forceinline__ float blo(unsigned u) { return __uint_as_float(u << 16); }
__device__ __forceinline__ float bhi(unsigned u) { return __uint_as_float(u & 0xFFFF0000u); }
__device__ __forceinline__ unsigned short f2b(float f) {   // round-to-nearest-even
    unsigned u = __float_as_uint(f);
    return (unsigned short)((u + 0x7FFFu + ((u >> 16) & 1u)) >> 16);
}

// ---- init: fixed-stride bucket cursors ----
__global__ void k_init(int* __restrict__ cursor) {
    int i = blockIdx.x * blockDim.x + threadIdx.x;
    if (i < NB) cursor[i] = i * CAP;
}

// ---- single-pass bucket scatter: LDS-stage chunk, LDS hist, global reserve, scatter ----
__global__ __launch_bounds__(256) void p12(const int* __restrict__ src,
        const int* __restrict__ dst, const float* __restrict__ w,
        int* __restrict__ cursor, int2* __restrict__ stage) {
    __shared__ unsigned se[CHUNK];
    __shared__ float    sw[CHUNK];
    __shared__ int      lh[NB];
    int t = threadIdx.x;
    for (int i = t; i < NB; i += 256) lh[i] = 0;
    __syncthreads();
    int e0 = blockIdx.x * CHUNK;
    for (int i = t; i < CHUNK; i += 256) {
        int e = e0 + i;
        unsigned d = (unsigned)dst[e];
        unsigned s = (unsigned)src[e];
        float wv = w[e];
        unsigned pk = 0xFFFFFFFFu;   // invalid marker
        if (d < NN) {
            pk = (s & 0xFFFFu) | ((d & 63u) << 16) | ((d >> 6) << 22);
            atomicAdd(&lh[d >> 6], 1);
        }
        se[i] = pk;
        sw[i] = wv;
    }
    __syncthreads();
    for (int i = t; i < NB; i += 256) {
        int c = lh[i];
        lh[i] = c ? atomicAdd(&cursor[i], c) : 0;   // lh becomes global write cursor
    }
    __syncthreads();
    for (int i = t; i < CHUNK; i += 256) {
        unsigned pk = se[i];
        if (pk != 0xFFFFFFFFu) {
            int bucket = (int)(pk >> 22);
            int pos = atomicAdd(&lh[bucket], 1);    // LDS atomic
            if (pos < (bucket + 1) * CAP)
                stage[pos] = make_int2((int)(pk & 0x3FFFFFu), __float_as_int(sw[i]));
        }
    }
}

// ---- per-bucket row sort: stage -> csr; emit row_ptr/row_deg/dinv ----
__global__ __launch_bounds__(256) void p3_sort(const int2* __restrict__ stage,
        const int* __restrict__ cursor, int2* __restrict__ csr,
        int* __restrict__ row_ptr, int* __restrict__ row_deg, float* __restrict__ dinv) {
    __shared__ int   hist[64];
    __shared__ int   cur[64];
    __shared__ float wsum[64];
    int b = blockIdx.x, t = threadIdx.x;
    int g0 = b * CAP, g1 = cursor[b];
    if (t < 64) { hist[t] = 0; wsum[t] = 0.f; }
    __syncthreads();
    for (int j = g0 + t; j < g1; j += 256) {
        int2 pk = stage[j];
        int r = (pk.x >> 16) & 63;
        atomicAdd(&hist[r], 1);
        atomicAdd(&wsum[r], __int_as_float(pk.y));   // fused weighted degree
    }
    __syncthreads();
    if (t == 0) {
        int s = g0;
        for (int r = 0; r < 64; ++r) { cur[r] = s; s += hist[r]; }
    }
    __syncthreads();
    if (t < 64) {
        int n = b * 64 + t;
        if (n < NN) {
            row_ptr[n] = cur[t];
            row_deg[n] = hist[t];
            dinv[n] = rsqrtf(wsum[t] + 1.0f);
        }
    }
    __syncthreads();
    for (int j = g0 + t; j < g1; j += 256) {
        int2 pk = stage[j];
        int r = (pk.x >> 16) & 63;
        int pos = atomicAdd(&cur[r], 1);
        csr[pos] = make_int2(pk.x & 0xFFFF, pk.y);
    }
}

// hp[N,64] = bf16( dinv[r] * (x[N,64] @ W[64,64]) ); 16 rows/block
__global__ __launch_bounds__(256) void gemm_pre_kernel(const float* __restrict__ x,
        const float* __restrict__ W, const float* __restrict__ dinv,
        unsigned short* __restrict__ hp) {
    __shared__ float xs[16][64];
    int t = threadIdx.x;
    int base = blockIdx.x * 16;
    for (int idx = t; idx < 16 * 64; idx += 256)
        xs[idx >> 6][idx & 63] = x[(size_t)(base + (idx >> 6)) * 64 + (idx & 63)];
    __syncthreads();
    int col = t & 63, rq = t >> 6;
    float wc[64];
#pragma unroll
    for (int k = 0; k < 64; ++k) wc[k] = W[k * 64 + col];
    float acc0 = 0.f, acc1 = 0.f, acc2 = 0.f, acc3 = 0.f;
#pragma unroll
    for (int k = 0; k < 64; ++k) {
        float wk = wc[k];
        acc0 += xs[rq     ][k] * wk;
        acc1 += xs[rq +  4][k] * wk;
        acc2 += xs[rq +  8][k] * wk;
        acc3 += xs[rq + 12][k] * wk;
    }
    int r = base + rq;
    hp[(size_t)(r     ) * 64 + col] = f2b(dinv[r     ] * acc0);
    hp[(size_t)(r +  4) * 64 + col] = f2b(dinv[r +  4] * acc1);
    hp[(size_t)(r +  8) * 64 + col] = f2b(dinv[r +  8] * acc2);
    hp[(size_t)(r + 12) * 64 + col] = f2b(dinv[r + 12] * acc3);
}

// ---- wave-per-node gather: lane l = (edge-slot l>>3, feature-octet l&7).
// Each dwordx4 load fetches 8 DISTINCT hp rows per instruction (one per slot);
// two batches issued back-to-back = 16 lines in flight, no shuffle on the
// critical path. Epilogue: 3-round xor butterfly combines the 8 edge-slots.
__device__ __forceinline__ void gather_wave(int n, int slot, int fo,
        const int* __restrict__ row_ptr, const int* __restrict__ row_deg,
        const int2* __restrict__ csr, const uint4* __restrict__ hp4,
        float acc[8]) {
    int s0 = row_ptr[n], s1 = s0 + row_deg[n];
    // self term (weight 1): only slot 0 keeps it
    uint4 sv = hp4[(size_t)n * 8 + fo];
    bool keep = (slot == 0);
    acc[0] = keep ? blo(sv.x) : 0.f;  acc[1] = keep ? bhi(sv.x) : 0.f;
    acc[2] = keep ? blo(sv.y) : 0.f;  acc[3] = keep ? bhi(sv.y) : 0.f;
    acc[4] = keep ? blo(sv.z) : 0.f;  acc[5] = keep ? bhi(sv.z) : 0.f;
    acc[6] = keep ? blo(sv.w) : 0.f;  acc[7] = keep ? bhi(sv.w) : 0.f;
    for (int base = s0; base < s1; base += 16) {
        int j0 = base + slot, j1 = base + 8 + slot;
        int src0 = 0; float w0 = 0.f;
        int src1 = 0; float w1 = 0.f;
        if (j0 < s1) { int2 pk = csr[j0]; src0 = pk.x; w0 = __int_as_float(pk.y); }
        if (j1 < s1) { int2 pk = csr[j1]; src1 = pk.x; w1 = __int_as_float(pk.y); }
        uint4 u0 = hp4[(size_t)src0 * 8 + fo];   // 8 lines (one per slot)
        uint4 u1 = hp4[(size_t)src1 * 8 + fo];   // 8 more, independent
        acc[0] += w0 * blo(u0.x);  acc[1] += w0 * bhi(u0.x);
        acc[2] += w0 * blo(u0.y);  acc[3] += w0 * bhi(u0.y);
        acc[4] += w0 * blo(u0.z);  acc[5] += w0 * bhi(u0.z);
        acc[6] += w0 * blo(u0.w);  acc[7] += w0 * bhi(u0.w);
        acc[0] += w1 * blo(u1.x);  acc[1] += w1 * bhi(u1.x);
        acc[2] += w1 * blo(u1.y);  acc[3] += w1 * bhi(u1.y);
        acc[4] += w1 * blo(u1.z);  acc[5] += w1 * bhi(u1.z);
        acc[6] += w1 * blo(u1.w);  acc[7] += w1 * bhi(u1.w);
    }
#pragma unroll
    for (int m = 8; m <= 32; m <<= 1) {
#pragma unroll
        for (int i = 0; i < 8; ++i) acc[i] += __shfl_xor(acc[i], m, 64);
    }
    // now every lane holds the full sums for features fo*8 .. fo*8+7
}

// fused: gather(hp_cur) -> y = relu(dinv*g+b) -> hp_next = bf16(dinv * (y @ Wn))
// 1024 threads = 16 waves = 16 nodes per block; GEMM on 16x64 LDS tile.
__global__ __launch_bounds__(1024) void fused_kernel(const int* __restrict__ row_ptr,
        const int* __restrict__ row_deg, const int2* __restrict__ csr,
        const float* __restrict__ dinv, const uint4* __restrict__ hp_cur,
        const float* __restrict__ bias, const float* __restrict__ Wn,
        unsigned short* __restrict__ hp_next) {
    __shared__ float ys[16][64];
    int t = threadIdx.x;
    int wid = t >> 6, lane = t & 63, slot = lane >> 3, fo = lane & 7;
    int n = blockIdx.x * 16 + wid;
    float acc[8];
    gather_wave(n, slot, fo, row_ptr, row_deg, csr, hp_cur, acc);
    if (slot == 0) {
        float dv = dinv[n];
        float4 b0v = ((const float4*)bias)[fo * 2];
        float4 b1v = ((const float4*)bias)[fo * 2 + 1];
        float4 y0, y1;
        y0.x = fmaxf(dv * acc[0] + b0v.x, 0.f);
        y0.y = fmaxf(dv * acc[1] + b0v.y, 0.f);
        y0.z = fmaxf(dv * acc[2] + b0v.z, 0.f);
        y0.w = fmaxf(dv * acc[3] + b0v.w, 0.f);
        y1.x = fmaxf(dv * acc[4] + b1v.x, 0.f);
        y1.y = fmaxf(dv * acc[5] + b1v.y, 0.f);
        y1.z = fmaxf(dv * acc[6] + b1v.z, 0.f);
        y1.w = fmaxf(dv * acc[7] + b1v.w, 0.f);
        ((float4*)&ys[wid][fo * 8])[0] = y0;
        ((float4*)&ys[wid][fo * 8])[1] = y1;
    }
    __syncthreads();
    // GEMM: row rq = t>>6, col = t&63 (one output per thread)
    int col = lane, rq = wid;
    float wc[64];
#pragma unroll
    for (int k = 0; k < 64; ++k) wc[k] = Wn[k * 64 + col];
    float a = 0.f;
#pragma unroll
    for (int k = 0; k < 64; ++k) a += ys[rq][k] * wc[k];
    int r = blockIdx.x * 16 + rq;
    hp_next[(size_t)r * 64 + col] = f2b(dinv[r] * a);
}

// final layer: gather + bias + relu -> fp32 out
__global__ __launch_bounds__(1024) void final_kernel(const int* __restrict__ row_ptr,
        const int* __restrict__ row_deg, const int2* __restrict__ csr,
        const float* __restrict__ dinv, const uint4* __restrict__ hp_cur,
        const float* __restrict__ bias, float* __restrict__ out) {
    int t = threadIdx.x;
    int wid = t >> 6, lane = t & 63, slot = lane >> 3, fo = lane & 7;
    int n = blockIdx.x * 16 + wid;
    float acc[8];
    gather_wave(n, slot, fo, row_ptr, row_deg, csr, hp_cur, acc);
    if (slot == 0) {
        float dv = dinv[n];
        float4 b0v = ((const float4*)bias)[fo * 2];
        float4 b1v = ((const float4*)bias)[fo * 2 + 1];
        float4 r0, r1;
        r0.x = fmaxf(dv * acc[0] + b0v.x, 0.f);
        r0.y = fmaxf(dv * acc[1] + b0v.y, 0.f);
        r0.z = fmaxf(dv * acc[2] + b0v.z, 0.f);
        r0.w = fmaxf(dv * acc[3] + b0v.w, 0.f);
        r1.x = fmaxf(dv * acc[4] + b1v.x, 0.f);
        r1.y = fmaxf(dv * acc[5] + b1v.y, 0.f);
        r1.z = fmaxf(dv * acc[6] + b1v.z, 0.f);
        r1.w = fmaxf(dv * acc[7] + b1v.w, 0.f);
        float4* orow = (float4*)(out + (size_t)n * 64 + fo * 8);
        orow[0] = r0;
        orow[1] = r1;
    }
}

extern "C" void kernel_launch(void* const* d_in, const int* in_sizes, int n_in,
                              void* d_out, int out_size, void* d_ws, size_t ws_size,
                              hipStream_t stream) {
    const float* x  = (const float*)d_in[0];
    const int*   ei = (const int*)d_in[1];    // int32 [2, NE] flat
    const float* ew = (const float*)d_in[2];
    const float* W0 = (const float*)d_in[3];
    const float* b0 = (const float*)d_in[4];
    const float* W1 = (const float*)d_in[5];
    const float* b1 = (const float*)d_in[6];
    const float* W2 = (const float*)d_in[7];
    const float* b2 = (const float*)d_in[8];
    float*       out = (float*)d_out;

    const int* src = ei;
    const int* dst = ei + NE;

    // workspace layout: hp arrays right after csr for 16B alignment (uint4 loads)
    int2*  stage   = (int2*)d_ws;                        // CAPTOT      (9.6 MB)
    int2*  csr     = stage + CAPTOT;                     // CAPTOT      (9.6 MB)
    unsigned short* hpA = (unsigned short*)(csr + CAPTOT);   // NN*64 bf16 (6.4 MB, 16B-aligned)
    unsigned short* hpB = hpA + (size_t)NN * 64;             // NN*64 bf16 (6.4 MB)
    int*   cursor  = (int*)(hpB + (size_t)NN * 64);      // NB
    int*   row_ptr = cursor + NB;                        // NN
    int*   row_deg = row_ptr + NN;                       // NN
    float* dinv    = (float*)(row_deg + NN);             // NN

    // ---- CSR build (once, shared by all 3 layers) ----
    k_init<<<1, 1024, 0, stream>>>(cursor);
    p12<<<NBLK, 256, 0, stream>>>(src, dst, ew, cursor, stage);
    p3_sort<<<NB, 256, 0, stream>>>(stage, cursor, csr, row_ptr, row_deg, dinv);

    // ---- layer pipeline: gemm0 -> fused(l0->l1) -> fused(l1->l2) -> final ----
    gemm_pre_kernel<<<NN / 16, 256, 0, stream>>>(x, W0, dinv, hpA);
    fused_kernel<<<NN / 16, 1024, 0, stream>>>(row_ptr, row_deg, csr, dinv,
            (const uint4*)hpA, b0, W1, hpB);
    fused_kernel<<<NN / 16, 1024, 0, stream>>>(row_ptr, row_deg, csr, dinv,
            (const uint4*)hpB, b1, W2, hpA);
    final_kernel<<<NN / 16, 1024, 0, stream>>>(row_ptr, row_deg, csr, dinv,
            (const uint4*)hpA, b2, out);
}

// Round 8
// 260.655 us; speedup vs baseline: 1.0445x; 1.0445x over previous
//
#include <hip/hip_runtime.h>

#define NN 50000
#define NE 800000
#define D  64
#define NB 782        // buckets of 64 nodes: ceil(50000/64)
#define NBLK 256      // p12 blocks
#define CHUNK 3125    // NBLK * CHUNK == NE exactly
#define CAP 1536      // per-bucket slot cap (mean 1024, +6 sigma ~ 1216)
#define CAPTOT (NB * CAP)
#define NTI 3125      // 16-node tiles: NN/16

// bf16 helpers (raw ushort storage, fp32 math)
__device__ __forceinline__ float blo(unsigned u) { return __uint_as_float(u << 16); }
__device__ __forceinline__ float bhi(unsigned u) { return __uint_as_float(u & 0xFFFF0000u); }
__device__ __forceinline__ unsigned short f2b(float f) {   // round-to-nearest-even
    unsigned u = __float_as_uint(f);
    return (unsigned short)((u + 0x7FFFu + ((u >> 16) & 1u)) >> 16);
}

// ---- init: fixed-stride bucket cursors ----
__global__ void k_init(int* __restrict__ cursor) {
    int i = blockIdx.x * blockDim.x + threadIdx.x;
    if (i < NB) cursor[i] = i * CAP;
}

// ---- single-pass bucket scatter: LDS-stage chunk, LDS hist, global reserve, scatter ----
__global__ __launch_bounds__(256) void p12(const int* __restrict__ src,
        const int* __restrict__ dst, const float* __restrict__ w,
        int* __restrict__ cursor, int2* __restrict__ stage) {
    __shared__ unsigned se[CHUNK];
    __shared__ float    sw[CHUNK];
    __shared__ int      lh[NB];
    int t = threadIdx.x;
    for (int i = t; i < NB; i += 256) lh[i] = 0;
    __syncthreads();
    int e0 = blockIdx.x * CHUNK;
    for (int i = t; i < CHUNK; i += 256) {
        int e = e0 + i;
        unsigned d = (unsigned)dst[e];
        unsigned s = (unsigned)src[e];
        float wv = w[e];
        unsigned pk = 0xFFFFFFFFu;   // invalid marker
        if (d < NN) {
            pk = (s & 0xFFFFu) | ((d & 63u) << 16) | ((d >> 6) << 22);
            atomicAdd(&lh[d >> 6], 1);
        }
        se[i] = pk;
        sw[i] = wv;
    }
    __syncthreads();
    for (int i = t; i < NB; i += 256) {
        int c = lh[i];
        lh[i] = c ? atomicAdd(&cursor[i], c) : 0;   // lh becomes global write cursor
    }
    __syncthreads();
    for (int i = t; i < CHUNK; i += 256) {
        unsigned pk = se[i];
        if (pk != 0xFFFFFFFFu) {
            int bucket = (int)(pk >> 22);
            int pos = atomicAdd(&lh[bucket], 1);    // LDS atomic
            if (pos < (bucket + 1) * CAP)
                stage[pos] = make_int2((int)(pk & 0x3FFFFFu), __float_as_int(sw[i]));
        }
    }
}

// ---- per-bucket row sort: stage -> csr; emit row_ptr/row_deg/dinv ----
__global__ __launch_bounds__(256) void p3_sort(const int2* __restrict__ stage,
        const int* __restrict__ cursor, int2* __restrict__ csr,
        int* __restrict__ row_ptr, int* __restrict__ row_deg, float* __restrict__ dinv) {
    __shared__ int   hist[64];
    __shared__ int   cur[64];
    __shared__ float wsum[64];
    int b = blockIdx.x, t = threadIdx.x;
    int g0 = b * CAP, g1 = cursor[b];
    if (t < 64) { hist[t] = 0; wsum[t] = 0.f; }
    __syncthreads();
    for (int j = g0 + t; j < g1; j += 256) {
        int2 pk = stage[j];
        int r = (pk.x >> 16) & 63;
        atomicAdd(&hist[r], 1);
        atomicAdd(&wsum[r], __int_as_float(pk.y));   // fused weighted degree
    }
    __syncthreads();
    if (t == 0) {
        int s = g0;
        for (int r = 0; r < 64; ++r) { cur[r] = s; s += hist[r]; }
    }
    __syncthreads();
    if (t < 64) {
        int n = b * 64 + t;
        if (n < NN) {
            row_ptr[n] = cur[t];
            row_deg[n] = hist[t];
            dinv[n] = rsqrtf(wsum[t] + 1.0f);
        }
    }
    __syncthreads();
    for (int j = g0 + t; j < g1; j += 256) {
        int2 pk = stage[j];
        int r = (pk.x >> 16) & 63;
        int pos = atomicAdd(&cur[r], 1);
        csr[pos] = make_int2(pk.x & 0xFFFF, pk.y);
    }
}

// hp halves = bf16( dinv[r] * (x[N,64] @ W[64,64]) ); 16 rows/block; NT x loads
__global__ __launch_bounds__(256) void gemm_pre_kernel(const float* __restrict__ x,
        const float* __restrict__ W, const float* __restrict__ dinv,
        unsigned short* __restrict__ hpL, unsigned short* __restrict__ hpH) {
    __shared__ float xs[16][64];
    int t = threadIdx.x;
    int base = blockIdx.x * 16;
    for (int idx = t; idx < 16 * 64; idx += 256)
        xs[idx >> 6][idx & 63] =
            __builtin_nontemporal_load(&x[(size_t)(base + (idx >> 6)) * 64 + (idx & 63)]);
    __syncthreads();
    int col = t & 63, rq = t >> 6;
    float wc[64];
#pragma unroll
    for (int k = 0; k < 64; ++k) wc[k] = W[k * 64 + col];
    float acc0 = 0.f, acc1 = 0.f, acc2 = 0.f, acc3 = 0.f;
#pragma unroll
    for (int k = 0; k < 64; ++k) {
        float wk = wc[k];
        acc0 += xs[rq     ][k] * wk;
        acc1 += xs[rq +  4][k] * wk;
        acc2 += xs[rq +  8][k] * wk;
        acc3 += xs[rq + 12][k] * wk;
    }
    unsigned short* hh = (col < 32) ? hpL : hpH;
    int hc = col & 31;
    int r = base + rq;
    hh[(size_t)(r     ) * 32 + hc] = f2b(dinv[r     ] * acc0);
    hh[(size_t)(r +  4) * 32 + hc] = f2b(dinv[r +  4] * acc1);
    hh[(size_t)(r +  8) * 32 + hc] = f2b(dinv[r +  8] * acc2);
    hh[(size_t)(r + 12) * 32 + hc] = f2b(dinv[r + 12] * acc3);
}

// mid gemm: hp_next halves = bf16( dinv[r] * (y[N,64] @ W) ); y read NT from halves
__global__ __launch_bounds__(256) void gemm_mid_kernel(const float* __restrict__ yL,
        const float* __restrict__ yH, const float* __restrict__ W,
        const float* __restrict__ dinv,
        unsigned short* __restrict__ hpL, unsigned short* __restrict__ hpH) {
    __shared__ float ys[16][64];
    int t = threadIdx.x;
    int base = blockIdx.x * 16;
    for (int idx = t; idx < 16 * 64; idx += 256) {
        int row = idx >> 6, c = idx & 63;
        const float* sp = (c < 32) ? &yL[(size_t)(base + row) * 32 + c]
                                   : &yH[(size_t)(base + row) * 32 + (c - 32)];
        ys[row][c] = __builtin_nontemporal_load(sp);
    }
    __syncthreads();
    int col = t & 63, rq = t >> 6;
    float wc[64];
#pragma unroll
    for (int k = 0; k < 64; ++k) wc[k] = W[k * 64 + col];
    float acc0 = 0.f, acc1 = 0.f, acc2 = 0.f, acc3 = 0.f;
#pragma unroll
    for (int k = 0; k < 64; ++k) {
        float wk = wc[k];
        acc0 += ys[rq     ][k] * wk;
        acc1 += ys[rq +  4][k] * wk;
        acc2 += ys[rq +  8][k] * wk;
        acc3 += ys[rq + 12][k] * wk;
    }
    unsigned short* hh = (col < 32) ? hpL : hpH;
    int hc = col & 31;
    int r = base + rq;
    hh[(size_t)(r     ) * 32 + hc] = f2b(dinv[r     ] * acc0);
    hh[(size_t)(r +  4) * 32 + hc] = f2b(dinv[r +  4] * acc1);
    hh[(size_t)(r +  8) * 32 + hc] = f2b(dinv[r +  8] * acc2);
    hh[(size_t)(r + 12) * 32 + hc] = f2b(dinv[r + 12] * acc3);
}

// ---- half-feature gather: blocks on XCDs 0-3 do half L, XCDs 4-7 do half H
// (bid&7 = XCD under round-robin dispatch; perf heuristic only).
// Per-XCD hot set = one 3.2MB hp half -> L2-resident. csr read NT (streaming),
// y/out written NT. Quarter-wave per node, round-0 shuffle loop at half width;
// per-node per-feature summation order is bitwise-identical to round 0.
__global__ __launch_bounds__(256) void gather_half_kernel(const int* __restrict__ row_ptr,
        const int* __restrict__ row_deg, const int2* __restrict__ csr,
        const float* __restrict__ dinv, const unsigned* __restrict__ hpL,
        const unsigned* __restrict__ hpH, const float* __restrict__ bias,
        float* __restrict__ outL, float* __restrict__ outH, int orow) {
    int bid = blockIdx.x;
    int g = bid >> 3, r7 = bid & 7;
    int half = r7 >> 2;
    int tile = g * 4 + (r7 & 3);
    if (tile >= NTI) return;
    const unsigned* hp = half ? hpH : hpL;
    const float2* bb2 = (const float2*)(bias + half * 32);
    float* ob = half ? outH : outL;

    int t = threadIdx.x;
    int lane = t & 63, q = lane >> 4, fq = lane & 15;
    int ni = ((t >> 6) << 2) + q;
    int n = tile * 16 + ni;
    int qbase = q << 4;

    int s0 = row_ptr[n], s1 = s0 + row_deg[n];
    unsigned self = hp[(size_t)n * 16 + fq];
    float ax = blo(self), ay = bhi(self);
    float bx = 0.f, by = 0.f;
    for (int base = s0; base < s1; base += 16) {
        int j = base + fq;
        int si = 0; float wl = 0.f;
        if (j < s1) {
            long long pv = __builtin_nontemporal_load((const long long*)(csr + j));
            si = (int)(unsigned)(pv & 0xFFFFFFFFll);
            wl = __int_as_float((int)(pv >> 32));
        }
        int m = s1 - base; if (m > 16) m = 16;
        int jj = 0;
        for (; jj + 4 <= m; jj += 4) {
            int a0 = __shfl(si, qbase + jj + 0); float w0 = __shfl(wl, qbase + jj + 0);
            int a1 = __shfl(si, qbase + jj + 1); float w1 = __shfl(wl, qbase + jj + 1);
            int a2 = __shfl(si, qbase + jj + 2); float w2 = __shfl(wl, qbase + jj + 2);
            int a3 = __shfl(si, qbase + jj + 3); float w3 = __shfl(wl, qbase + jj + 3);
            unsigned u0 = hp[(size_t)a0 * 16 + fq];
            unsigned u1 = hp[(size_t)a1 * 16 + fq];
            unsigned u2 = hp[(size_t)a2 * 16 + fq];
            unsigned u3 = hp[(size_t)a3 * 16 + fq];
            ax += w0 * blo(u0); ay += w0 * bhi(u0);
            bx += w1 * blo(u1); by += w1 * bhi(u1);
            ax += w2 * blo(u2); ay += w2 * bhi(u2);
            bx += w3 * blo(u3); by += w3 * bhi(u3);
        }
        for (; jj < m; ++jj) {
            int a0 = __shfl(si, qbase + jj); float w0 = __shfl(wl, qbase + jj);
            unsigned u0 = hp[(size_t)a0 * 16 + fq];
            ax += w0 * blo(u0); ay += w0 * bhi(u0);
        }
    }
    float dv = dinv[n];
    float2 bb = bb2[fq];
    float2 yv;
    yv.x = fmaxf(dv * (ax + bx) + bb.x, 0.f);
    yv.y = fmaxf(dv * (ay + by) + bb.y, 0.f);
    union { float2 f; double d; } u; u.f = yv;
    __builtin_nontemporal_store(u.d, (double*)((float2*)(ob + (size_t)n * orow) + fq));
}

extern "C" void kernel_launch(void* const* d_in, const int* in_sizes, int n_in,
                              void* d_out, int out_size, void* d_ws, size_t ws_size,
                              hipStream_t stream) {
    const float* x  = (const float*)d_in[0];
    const int*   ei = (const int*)d_in[1];    // int32 [2, NE] flat
    const float* ew = (const float*)d_in[2];
    const float* W0 = (const float*)d_in[3];
    const float* b0 = (const float*)d_in[4];
    const float* W1 = (const float*)d_in[5];
    const float* b1 = (const float*)d_in[6];
    const float* W2 = (const float*)d_in[7];
    const float* b2 = (const float*)d_in[8];
    float*       out = (float*)d_out;

    const int* src = ei;
    const int* dst = ei + NE;

    // workspace layout (~46 MB): 8B-aligned arrays in order
    int2*  stage = (int2*)d_ws;                          // CAPTOT (9.6 MB)
    int2*  csr   = stage + CAPTOT;                       // CAPTOT (9.6 MB)
    float* yL    = (float*)(csr + CAPTOT);               // NN*32 fp32 (6.4 MB)
    float* yH    = yL + (size_t)NN * 32;                 // NN*32 fp32 (6.4 MB)
    unsigned short* hpAL = (unsigned short*)(yH + (size_t)NN * 32);  // NN*32 bf16 (3.2 MB)
    unsigned short* hpAH = hpAL + (size_t)NN * 32;       // 3.2 MB
    unsigned short* hpBL = hpAH + (size_t)NN * 32;       // 3.2 MB
    unsigned short* hpBH = hpBL + (size_t)NN * 32;       // 3.2 MB
    int*   cursor  = (int*)(hpBH + (size_t)NN * 32);     // NB
    int*   row_ptr = cursor + NB;                        // NN
    int*   row_deg = row_ptr + NN;                       // NN
    float* dinv    = (float*)(row_deg + NN);             // NN

    // ---- CSR build (once, shared by all 3 layers) ----
    k_init<<<1, 1024, 0, stream>>>(cursor);
    p12<<<NBLK, 256, 0, stream>>>(src, dst, ew, cursor, stage);
    p3_sort<<<NB, 256, 0, stream>>>(stage, cursor, csr, row_ptr, row_deg, dinv);

    // ---- layer pipeline ----
    gemm_pre_kernel<<<NTI, 256, 0, stream>>>(x, W0, dinv, hpAL, hpAH);
    gather_half_kernel<<<NB * 8, 256, 0, stream>>>(row_ptr, row_deg, csr, dinv,
            (const unsigned*)hpAL, (const unsigned*)hpAH, b0, yL, yH, 32);
    gemm_mid_kernel<<<NTI, 256, 0, stream>>>(yL, yH, W1, dinv, hpBL, hpBH);
    gather_half_kernel<<<NB * 8, 256, 0, stream>>>(row_ptr, row_deg, csr, dinv,
            (const unsigned*)hpBL, (const unsigned*)hpBH, b1, yL, yH, 32);
    gemm_mid_kernel<<<NTI, 256, 0, stream>>>(yL, yH, W2, dinv, hpAL, hpAH);
    gather_half_kernel<<<NB * 8, 256, 0, stream>>>(row_ptr, row_deg, csr, dinv,
            (const unsigned*)hpAL, (const unsigned*)hpAH, b2, out, out + 32, 64);
}